// Round 12
// baseline (984.801 us; speedup 1.0000x reference)
//
#include <hip/hip_runtime.h>

#define HW 9216   // 96*96

typedef __bf16 bf16x8 __attribute__((ext_vector_type(8)));
typedef __bf16 bf16x4 __attribute__((ext_vector_type(4)));
typedef float  f32x4  __attribute__((ext_vector_type(4)));
typedef unsigned short u16;

// ---------------------------------------------------------------------------
// Split fp32 x into hi/lo bf16 pixel-major groups: PK[b][g][px][8], g=0..7.
// grid = 128 blocks (b*8+g), 256 threads.
// ---------------------------------------------------------------------------
__global__ void split_x(const float* __restrict__ x, u16* __restrict__ PKH,
                        u16* __restrict__ PKL) {
    int b = blockIdx.x >> 3, g = blockIdx.x & 7;
    for (int px = threadIdx.x; px < HW; px += 256) {
        bf16x8 Hv, Lv;
#pragma unroll
        for (int i = 0; i < 8; ++i) {
            float v = x[((size_t)b * 64 + g * 8 + i) * HW + px];
            __bf16 hh = (__bf16)v;
            Hv[i] = hh;
            Lv[i] = (__bf16)(v - (float)hh);
        }
        size_t base = ((size_t)(b * 40 + g) * HW + px) * 8;
        *(bf16x8*)(PKH + base) = Hv;
        *(bf16x8*)(PKL + base) = Lv;
    }
}

// ---------------------------------------------------------------------------
// Pooled mean from fp32 x (layer 0 only). grid = B*64, 256 threads.
// ---------------------------------------------------------------------------
__global__ void pooled_kernel(const float* __restrict__ src,
                              float* __restrict__ pooled) {
    int b = blockIdx.x >> 6;
    int c = blockIdx.x & 63;
    const float4* p4 = (const float4*)(src + ((size_t)b * 64 + c) * HW);
    float s = 0.f;
    for (int i = threadIdx.x; i < HW / 4; i += 256) {
        float4 v = p4[i];
        s += (v.x + v.y) + (v.z + v.w);
    }
    for (int off = 32; off; off >>= 1) s += __shfl_down(s, off, 64);
    __shared__ float red[4];
    int lane = threadIdx.x & 63, wid = threadIdx.x >> 6;
    if (!lane) red[wid] = s;
    __syncthreads();
    if (!threadIdx.x)
        pooled[b * 320 + c] = (red[0] + red[1] + red[2] + red[3]) * (1.0f / HW);
}

// ---------------------------------------------------------------------------
// Pooled mean from pk hi/lo layout. grid = 128 blocks (b*8+gr), 256 threads.
// ---------------------------------------------------------------------------
__global__ void pooled_pk(const u16* __restrict__ PKH, const u16* __restrict__ PKL,
                          float* __restrict__ pooled, int gbase, int pbase) {
    int b = blockIdx.x >> 3, gr = blockIdx.x & 7;
    const u16* bh = PKH + ((size_t)(b * 40 + gbase + gr) * HW) * 8;
    const u16* bl = PKL + ((size_t)(b * 40 + gbase + gr) * HW) * 8;
    float acc[8];
#pragma unroll
    for (int i = 0; i < 8; ++i) acc[i] = 0.f;
    for (int px = threadIdx.x; px < HW; px += 256) {
        bf16x8 H = *(const bf16x8*)(bh + px * 8);
        bf16x8 L = *(const bf16x8*)(bl + px * 8);
#pragma unroll
        for (int i = 0; i < 8; ++i) acc[i] += (float)H[i] + (float)L[i];
    }
#pragma unroll
    for (int i = 0; i < 8; ++i)
        for (int off = 32; off; off >>= 1) acc[i] += __shfl_down(acc[i], off, 64);
    __shared__ float red[4][8];
    int lane = threadIdx.x & 63, wid = threadIdx.x >> 6;
    if (!lane) {
#pragma unroll
        for (int i = 0; i < 8; ++i) red[wid][i] = acc[i];
    }
    __syncthreads();
    if (threadIdx.x < 8) {
        float s = red[0][threadIdx.x] + red[1][threadIdx.x] +
                  red[2][threadIdx.x] + red[3][threadIdx.x];
        pooled[b * 320 + pbase + gr * 8 + threadIdx.x] = s * (1.0f / HW);
    }
}

// ---------------------------------------------------------------------------
// Attention MLP + softmax + per-sample bias. grid = B blocks, 128 threads.
// ---------------------------------------------------------------------------
__global__ void attn_kernel(const float* __restrict__ pooled,
                            const float* __restrict__ aw1, const float* __restrict__ ab1,
                            const float* __restrict__ aw2, const float* __restrict__ ab2,
                            const float* __restrict__ bconst,
                            float* __restrict__ attn, float* __restrict__ bk,
                            int cin, int hid) {
    int b = blockIdx.x;
    int t = threadIdx.x;
    __shared__ float sp[320];
    __shared__ float sh[80];
    __shared__ float sl[8];
    __shared__ float sa[8];
    for (int c = t; c < cin; c += 128) sp[c] = pooled[b * 320 + c];
    __syncthreads();
    if (t < hid) {
        float acc = ab1[t];
        const float* row = aw1 + (size_t)t * cin;
        for (int c = 0; c < cin; ++c) acc = fmaf(row[c], sp[c], acc);
        sh[t] = acc > 0.f ? acc : 0.f;
    }
    __syncthreads();
    if (t < 8) {
        float acc = ab2[t];
        const float* row = aw2 + t * hid;
        for (int j = 0; j < hid; ++j) acc = fmaf(row[j], sh[j], acc);
        sl[t] = acc;
    }
    __syncthreads();
    if (t == 0) {
        float m = sl[0];
        for (int k = 1; k < 8; ++k) m = fmaxf(m, sl[k]);
        float e[8], ssum = 0.f;
        for (int k = 0; k < 8; ++k) { e[k] = expf(sl[k] - m); ssum += e[k]; }
        float inv = 1.0f / ssum;
        for (int k = 0; k < 8; ++k) { sa[k] = e[k] * inv; attn[b * 8 + k] = sa[k]; }
    }
    __syncthreads();
    if (t < 64) {
        float acc = 0.f;
        for (int k = 0; k < 8; ++k) acc = fmaf(sa[k], bconst[k * 64 + t], acc);
        bk[b * 64 + t] = acc;
    }
}

// ---------------------------------------------------------------------------
// Weight mix + hi/lo bf16 split, packed in A-fragment order (unchanged).
// ---------------------------------------------------------------------------
__global__ __launch_bounds__(256)
void pack_weights(const float* __restrict__ w, const float* __restrict__ attn,
                  u16* __restrict__ PWH, u16* __restrict__ PWL, int cin) {
    __shared__ float sa[128];
    int t = threadIdx.x;
    if (t < 128) sa[t] = attn[t];
    __syncthreads();
    int g = blockIdx.x * 256 + t;
    int nch = cin >> 5;
    if (g >= nch * 2304) return;   // 9 taps * 4 kg * 64 oc
    int oc = g & 63;
    int r = g >> 6;
    int kg = r & 3;
    int ct = r >> 2;
    int tap = ct % 9;
    int chunk = ct / 9;
    int c0 = chunk * 32 + kg * 8;
    float wv[8][8];   // [k][i]
#pragma unroll
    for (int k = 0; k < 8; ++k)
#pragma unroll
        for (int i = 0; i < 8; ++i)
            wv[k][i] = w[(((size_t)k * 64 + oc) * cin + c0 + i) * 9 + tap];
#pragma unroll 1
    for (int b = 0; b < 16; ++b) {
        bf16x8 Hv, Lv;
#pragma unroll
        for (int i = 0; i < 8; ++i) {
            float v = 0.f;
#pragma unroll
            for (int k = 0; k < 8; ++k) v = fmaf(sa[b * 8 + k], wv[k][i], v);
            __bf16 hh = (__bf16)v;
            Hv[i] = hh;
            Lv[i] = (__bf16)(v - (float)hh);
        }
        size_t base = ((size_t)(b * nch + chunk) * 9 + tap) * 2048 + kg * 512 + oc * 8;
        *(bf16x8*)(PWH + base) = Hv;
        *(bf16x8*)(PWL + base) = Lv;
    }
}

// ---------------------------------------------------------------------------
// MFMA conv, staging from pre-split pk features with register prefetch.
// Block = 256 thr (4 waves) -> 64oc x 192px (2 rows). grid = (48, 16).
// Per chunk: {issue next-chunk loads; compute current; sync; ds_write; sync}.
// Non-FINAL epilogue writes hi/lo pk groups at ogbase; FINAL writes fp32 out.
// ---------------------------------------------------------------------------
template <int CIN, bool FINAL>
__global__ __launch_bounds__(256, 2)
void conv_mfma(const float* __restrict__ x, u16* __restrict__ PKH,
               u16* __restrict__ PKL, const u16* __restrict__ PWH,
               const u16* __restrict__ PWL, const float* __restrict__ bk,
               float* __restrict__ out, int ogbase)
{
    constexpr int NCHK = CIN / 32;
    const int b  = blockIdx.y;
    const int h0 = blockIdx.x * 2;
    const int t  = threadIdx.x;
    const int w  = t >> 6;
    const int l  = t & 63;
    const int l15 = l & 15;
    const int l4  = l >> 4;
    const int orow  = w >> 1;
    const int ocol0 = (w & 1) * 48;

    __shared__ bf16x8 sX[2][1600];   // [hi/lo][(row*100+col)*4 + S]

    f32x4 acc[4][3];
#pragma unroll
    for (int q = 0; q < 4; ++q)
#pragma unroll
        for (int pf = 0; pf < 3; ++pf) acc[q][pf] = (f32x4){0.f, 0.f, 0.f, 0.f};

    bf16x8 zv;
#pragma unroll
    for (int i = 0; i < 8; ++i) zv[i] = (__bf16)0.f;

    bf16x8 ph[7], pl[7];   // next-chunk staging registers (static-indexed)

    const int aoff = l4 * 512 + l15 * 8;   // A-frag lane offset (u16 units)

    // ---- issue chunk-0 loads ----
    {
        int gg = 0 * 4 + w;
        const u16* bh = PKH + ((size_t)(b * 40 + gg) * HW) * 8;
        const u16* bl = PKL + ((size_t)(b * 40 + gg) * HW) * 8;
#pragma unroll
        for (int j = 0; j < 7; ++j) {
            int s = l + 64 * j;
            if (s < 392) {
                int row = s / 98, col = s - row * 98;
                int rin = h0 - 1 + row, ci = col - 1;
                bool ok = ((unsigned)rin < 96u) && ((unsigned)ci < 96u);
                size_t off = (size_t)(rin * 96 + ci) * 8;
                ph[j] = ok ? *(const bf16x8*)(bh + off) : zv;
                pl[j] = ok ? *(const bf16x8*)(bl + off) : zv;
            }
        }
    }
    // ---- write chunk 0 to LDS ----
#pragma unroll
    for (int j = 0; j < 7; ++j) {
        int s = l + 64 * j;
        if (s < 392) {
            int row = s / 98, col = s - row * 98;
            int S = (w ^ (col & 3) ^ ((col >> 2) & 3)) & 3;
            int slot = (row * 100 + col) * 4 + S;
            sX[0][slot] = ph[j];
            sX[1][slot] = pl[j];
        }
    }
    __syncthreads();

#pragma unroll 1
    for (int chunk = 0; chunk < NCHK; ++chunk) {
        // ---- issue next chunk's loads (overlap with compute below) ----
        if (chunk + 1 < NCHK) {
            int gg = (chunk + 1) * 4 + w;
            const u16* bh = PKH + ((size_t)(b * 40 + gg) * HW) * 8;
            const u16* bl = PKL + ((size_t)(b * 40 + gg) * HW) * 8;
#pragma unroll
            for (int j = 0; j < 7; ++j) {
                int s = l + 64 * j;
                if (s < 392) {
                    int row = s / 98, col = s - row * 98;
                    int rin = h0 - 1 + row, ci = col - 1;
                    bool ok = ((unsigned)rin < 96u) && ((unsigned)ci < 96u);
                    size_t off = (size_t)(rin * 96 + ci) * 8;
                    ph[j] = ok ? *(const bf16x8*)(bh + off) : zv;
                    pl[j] = ok ? *(const bf16x8*)(bl + off) : zv;
                }
            }
        }

        // ---- compute current chunk ----
        const u16* pwh = PWH + ((size_t)(b * NCHK + chunk) * 9) * 2048 + aoff;
        const u16* pwl = PWL + ((size_t)(b * NCHK + chunk) * 9) * 2048 + aoff;
#pragma unroll
        for (int tap = 0; tap < 9; ++tap) {
            const int kh = tap / 3, kw = tap % 3;
            bf16x8 Ah[4], Al[4];
#pragma unroll
            for (int q = 0; q < 4; ++q) {
                Ah[q] = *(const bf16x8*)(pwh + tap * 2048 + q * 128);
                Al[q] = *(const bf16x8*)(pwl + tap * 2048 + q * 128);
            }
#pragma unroll
            for (int pf = 0; pf < 3; ++pf) {
                int col = ocol0 + pf * 16 + l15 + kw;
                int row = orow + kh;
                int S = (l4 ^ (col & 3) ^ ((col >> 2) & 3)) & 3;
                int slot = (row * 100 + col) * 4 + S;
                bf16x8 Bh = sX[0][slot];
                bf16x8 Bl = sX[1][slot];
#pragma unroll
                for (int q = 0; q < 4; ++q) {
                    acc[q][pf] = __builtin_amdgcn_mfma_f32_16x16x32_bf16(Ah[q], Bh, acc[q][pf], 0, 0, 0);
                    acc[q][pf] = __builtin_amdgcn_mfma_f32_16x16x32_bf16(Ah[q], Bl, acc[q][pf], 0, 0, 0);
                    acc[q][pf] = __builtin_amdgcn_mfma_f32_16x16x32_bf16(Al[q], Bh, acc[q][pf], 0, 0, 0);
                }
            }
        }

        __syncthreads();   // all waves done reading sX
        if (chunk + 1 < NCHK) {
#pragma unroll
            for (int j = 0; j < 7; ++j) {
                int s = l + 64 * j;
                if (s < 392) {
                    int row = s / 98, col = s - row * 98;
                    int S = (w ^ (col & 3) ^ ((col >> 2) & 3)) & 3;
                    int slot = (row * 100 + col) * 4 + S;
                    sX[0][slot] = ph[j];
                    sX[1][slot] = pl[j];
                }
            }
            __syncthreads();   // writes visible before next compute
        }
    }

    // ---- epilogue ----
    const int orow_g = h0 + orow;
#pragma unroll
    for (int q = 0; q < 4; ++q) {
        if (FINAL) {
#pragma unroll
            for (int rg = 0; rg < 4; ++rg) {
                int oc = q * 16 + l4 * 4 + rg;
                float bias = bk[b * 64 + oc];
                float* op = out + ((size_t)b * 64 + oc) * HW + orow_g * 96;
                const float* xp = x + ((size_t)b * 64 + oc) * HW + orow_g * 96;
#pragma unroll
                for (int pf = 0; pf < 3; ++pf) {
                    int cc = ocol0 + pf * 16 + l15;
                    float v = acc[q][pf][rg] + bias;
                    op[cc] = 0.2f * v + xp[cc];
                }
            }
        } else {
            const int go = ogbase + 2 * q + (l4 >> 1);
            const int ib = (l4 & 1) * 4;
#pragma unroll
            for (int pf = 0; pf < 3; ++pf) {
                int cc = ocol0 + pf * 16 + l15;
                bf16x4 hv, lv;
#pragma unroll
                for (int rg = 0; rg < 4; ++rg) {
                    int oc = q * 16 + l4 * 4 + rg;
                    float v = acc[q][pf][rg] + bk[b * 64 + oc];
                    v = (v >= 0.f) ? v : 0.2f * v;
                    __bf16 hh = (__bf16)v;
                    hv[rg] = hh;
                    lv[rg] = (__bf16)(v - (float)hh);
                }
                size_t base = ((size_t)(b * 40 + go) * HW + orow_g * 96 + cc) * 8 + ib;
                *(bf16x4*)(PKH + base) = hv;
                *(bf16x4*)(PKL + base) = lv;
            }
        }
    }
}

// ---------------------------------------------------------------------------
extern "C" void kernel_launch(void* const* d_in, const int* in_sizes, int n_in,
                              void* d_out, int out_size, void* d_ws, size_t ws_size,
                              hipStream_t stream) {
    const float* x = (const float*)d_in[0];
    float* out = (float*)d_out;

    // ws layout (u16 units for PK/PW):
    u16* PKH = (u16*)d_ws;                         // [16][40][9216][8] hi
    u16* PKL = PKH + (size_t)16 * 40 * HW * 8;
    u16* PWH = PKL + (size_t)16 * 40 * HW * 8;     // packed hi weights
    u16* PWL = PWH + (size_t)16 * 10 * 9 * 2048;   // packed lo weights
    float* pooled = (float*)(PWL + (size_t)16 * 10 * 9 * 2048);   // [16][320]
    float* attn = pooled + 16 * 320;               // [16][8]
    float* bk = attn + 16 * 8;                     // [16][64]

    const int cins[5] = {64, 128, 192, 256, 320};
    dim3 cgrid(48, 16);

    split_x<<<dim3(128), 256, 0, stream>>>(x, PKH, PKL);

    for (int li = 0; li < 5; ++li) {
        const float* w   = (const float*)d_in[1 + li * 6 + 0];
        const float* bb  = (const float*)d_in[1 + li * 6 + 1];
        const float* aw1 = (const float*)d_in[1 + li * 6 + 2];
        const float* ab1 = (const float*)d_in[1 + li * 6 + 3];
        const float* aw2 = (const float*)d_in[1 + li * 6 + 4];
        const float* ab2 = (const float*)d_in[1 + li * 6 + 5];
        const int cin = cins[li];
        const int hid = cin / 4;
        const int nch = cin / 32;

        if (li == 0)
            pooled_kernel<<<dim3(16 * 64), 256, 0, stream>>>(x, pooled);
        else
            pooled_pk<<<dim3(128), 256, 0, stream>>>(PKH, PKL, pooled,
                                                     8 + 8 * (li - 1), li * 64);

        attn_kernel<<<dim3(16), 128, 0, stream>>>(pooled, aw1, ab1, aw2, ab2, bb,
                                                  attn, bk, cin, hid);

        pack_weights<<<dim3(9 * nch), 256, 0, stream>>>(w, attn, PWH, PWL, cin);

        const int ogbase = 8 + 8 * li;
        switch (li) {
            case 0: conv_mfma< 64, false><<<cgrid, 256, 0, stream>>>(x, PKH, PKL, PWH, PWL, bk, out, ogbase); break;
            case 1: conv_mfma<128, false><<<cgrid, 256, 0, stream>>>(x, PKH, PKL, PWH, PWL, bk, out, ogbase); break;
            case 2: conv_mfma<192, false><<<cgrid, 256, 0, stream>>>(x, PKH, PKL, PWH, PWL, bk, out, ogbase); break;
            case 3: conv_mfma<256, false><<<cgrid, 256, 0, stream>>>(x, PKH, PKL, PWH, PWL, bk, out, ogbase); break;
            case 4: conv_mfma<320, true ><<<cgrid, 256, 0, stream>>>(x, PKH, PKL, PWH, PWL, bk, out, ogbase); break;
        }
    }
}

// Round 13
// 760.051 us; speedup vs baseline: 1.2957x; 1.2957x over previous
//
#include <hip/hip_runtime.h>

#define HW 9216   // 96*96

typedef __bf16 bf16x8 __attribute__((ext_vector_type(8)));
typedef float  f32x4  __attribute__((ext_vector_type(4)));
typedef unsigned short u16;

// ---------------------------------------------------------------------------
// Pooled mean over H,W for 64 channels. grid = B*64 blocks, 256 threads.
// ---------------------------------------------------------------------------
__global__ void pooled_kernel(const float* __restrict__ src, int b_stride, int ch_base,
                              float* __restrict__ pooled, int pout_base) {
    int b = blockIdx.x >> 6;
    int c = blockIdx.x & 63;
    const float4* p4 = (const float4*)(src + ((size_t)b * b_stride + ch_base + c) * HW);
    float s = 0.f;
    for (int i = threadIdx.x; i < HW / 4; i += 256) {
        float4 v = p4[i];
        s += (v.x + v.y) + (v.z + v.w);
    }
    for (int off = 32; off; off >>= 1) s += __shfl_down(s, off, 64);
    __shared__ float red[4];
    int lane = threadIdx.x & 63, wid = threadIdx.x >> 6;
    if (!lane) red[wid] = s;
    __syncthreads();
    if (!threadIdx.x)
        pooled[b * 320 + pout_base + c] = (red[0] + red[1] + red[2] + red[3]) * (1.0f / HW);
}

// ---------------------------------------------------------------------------
// Attention MLP + softmax + per-sample bias. grid = B blocks, 128 threads.
// ---------------------------------------------------------------------------
__global__ void attn_kernel(const float* __restrict__ pooled,
                            const float* __restrict__ aw1, const float* __restrict__ ab1,
                            const float* __restrict__ aw2, const float* __restrict__ ab2,
                            const float* __restrict__ bconst,
                            float* __restrict__ attn, float* __restrict__ bk,
                            int cin, int hid) {
    int b = blockIdx.x;
    int t = threadIdx.x;
    __shared__ float sp[320];
    __shared__ float sh[80];
    __shared__ float sl[8];
    __shared__ float sa[8];
    for (int c = t; c < cin; c += 128) sp[c] = pooled[b * 320 + c];
    __syncthreads();
    if (t < hid) {
        float acc = ab1[t];
        const float* row = aw1 + (size_t)t * cin;
        for (int c = 0; c < cin; ++c) acc = fmaf(row[c], sp[c], acc);
        sh[t] = acc > 0.f ? acc : 0.f;
    }
    __syncthreads();
    if (t < 8) {
        float acc = ab2[t];
        const float* row = aw2 + t * hid;
        for (int j = 0; j < hid; ++j) acc = fmaf(row[j], sh[j], acc);
        sl[t] = acc;
    }
    __syncthreads();
    if (t == 0) {
        float m = sl[0];
        for (int k = 1; k < 8; ++k) m = fmaxf(m, sl[k]);
        float e[8], ssum = 0.f;
        for (int k = 0; k < 8; ++k) { e[k] = expf(sl[k] - m); ssum += e[k]; }
        float inv = 1.0f / ssum;
        for (int k = 0; k < 8; ++k) { sa[k] = e[k] * inv; attn[b * 8 + k] = sa[k]; }
    }
    __syncthreads();
    if (t < 64) {
        float acc = 0.f;
        for (int k = 0; k < 8; ++k) acc = fmaf(sa[k], bconst[k * 64 + t], acc);
        bk[b * 64 + t] = acc;
    }
}

// ---------------------------------------------------------------------------
// Weight mix + hi/lo bf16 split, packed in A-fragment order:
//   PW[(b*nch + chunk)*9*2048 + tap*2048 + kg*512 + oc*8 + i]
// ---------------------------------------------------------------------------
__global__ __launch_bounds__(256)
void pack_weights(const float* __restrict__ w, const float* __restrict__ attn,
                  u16* __restrict__ PWH, u16* __restrict__ PWL, int cin) {
    __shared__ float sa[128];
    int t = threadIdx.x;
    if (t < 128) sa[t] = attn[t];
    __syncthreads();
    int g = blockIdx.x * 256 + t;
    int nch = cin >> 5;
    if (g >= nch * 2304) return;   // 9 taps * 4 kg * 64 oc
    int oc = g & 63;
    int r = g >> 6;
    int kg = r & 3;
    int ct = r >> 2;
    int tap = ct % 9;
    int chunk = ct / 9;
    int c0 = chunk * 32 + kg * 8;
    float wv[8][8];   // [k][i]
#pragma unroll
    for (int k = 0; k < 8; ++k)
#pragma unroll
        for (int i = 0; i < 8; ++i)
            wv[k][i] = w[(((size_t)k * 64 + oc) * cin + c0 + i) * 9 + tap];
#pragma unroll 1
    for (int b = 0; b < 16; ++b) {
        bf16x8 Hv, Lv;
#pragma unroll
        for (int i = 0; i < 8; ++i) {
            float v = 0.f;
#pragma unroll
            for (int k = 0; k < 8; ++k) v = fmaf(sa[b * 8 + k], wv[k][i], v);
            __bf16 hh = (__bf16)v;
            Hv[i] = hh;
            Lv[i] = (__bf16)(v - (float)hh);
        }
        size_t base = ((size_t)(b * nch + chunk) * 9 + tap) * 2048 + kg * 512 + oc * 8;
        *(bf16x8*)(PWH + base) = Hv;
        *(bf16x8*)(PWL + base) = Lv;
    }
}

// ---------------------------------------------------------------------------
// MFMA conv 3x3 pad 1, bf16x3 split, fp32 accumulate.
// Block = 256 thr (4 waves) -> 64oc x 192px (2 rows). grid = (48, 16).
// Wave w: row = w>>1, oc-half oh = w&1 (32 oc); 2 ocfrag x 6 pxfrag accs.
// (vs r10's 4q x 3pf: halves per-wave A-fragment L2 traffic.)
// LDS: X chunk [4 rows][98+2 cols][4 kg] of bf16x8, hi+lo, XOR-swizzled.
// ---------------------------------------------------------------------------
template <int CIN, bool FINAL>
__global__ __launch_bounds__(256, 2)
void conv_mfma(const float* __restrict__ x, const float* __restrict__ Fq,
               const u16* __restrict__ PWH, const u16* __restrict__ PWL,
               const float* __restrict__ bk, float* __restrict__ out, int OB)
{
    constexpr int NCHK = CIN / 32;
    const int b  = blockIdx.y;
    const int h0 = blockIdx.x * 2;
    const int t  = threadIdx.x;
    const int w  = t >> 6;
    const int l  = t & 63;
    const int l15 = l & 15;
    const int l4  = l >> 4;
    const int orow = w >> 1;
    const int oh   = w & 1;     // oc half: [oh*32, oh*32+32)

    __shared__ bf16x8 sX[2][1600];   // [hi/lo][(row*100+col)*4 + S]

    f32x4 acc[2][6];
#pragma unroll
    for (int q = 0; q < 2; ++q)
#pragma unroll
        for (int pf = 0; pf < 6; ++pf) acc[q][pf] = (f32x4){0.f, 0.f, 0.f, 0.f};

    const int aoff = l4 * 512 + l15 * 8;   // A-frag lane offset (u16 units)

#pragma unroll 1
    for (int chunk = 0; chunk < NCHK; ++chunk) {
        __syncthreads();
        const int c0 = chunk * 32;
        // ---- stage: wave w handles kg=w (channels c0+8w .. +8) ----
        for (int s = l; s < 392; s += 64) {   // 4 rows * 98 cols
            int row = s / 98;
            int col = s - row * 98;
            int rin = h0 - 1 + row;
            int ci  = col - 1;
            bool ok = ((unsigned)rin < 96u) && ((unsigned)ci < 96u);
            int off = rin * 96 + ci;
            bf16x8 Hv, Lv;
#pragma unroll
            for (int i = 0; i < 8; ++i) {
                int cg = c0 + w * 8 + i;
                const float* bp = (cg < 64)
                    ? (x + ((size_t)b * 64 + cg) * HW)
                    : (Fq + ((size_t)b * 256 + (cg - 64)) * HW);
                float v = ok ? bp[off] : 0.f;
                __bf16 hh = (__bf16)v;
                Hv[i] = hh;
                Lv[i] = (__bf16)(v - (float)hh);
            }
            int S = (w ^ (col & 3) ^ ((col >> 2) & 3)) & 3;
            int slot = (row * 100 + col) * 4 + S;
            sX[0][slot] = Hv;
            sX[1][slot] = Lv;
        }
        __syncthreads();

        const u16* pwh = PWH + ((size_t)(b * NCHK + chunk) * 9) * 2048 + aoff;
        const u16* pwl = PWL + ((size_t)(b * NCHK + chunk) * 9) * 2048 + aoff;
#pragma unroll
        for (int tap = 0; tap < 9; ++tap) {
            const int kh = tap / 3, kw = tap % 3;
            bf16x8 Ah[2], Al[2];
#pragma unroll
            for (int q = 0; q < 2; ++q) {
                Ah[q] = *(const bf16x8*)(pwh + tap * 2048 + (oh * 2 + q) * 128);
                Al[q] = *(const bf16x8*)(pwl + tap * 2048 + (oh * 2 + q) * 128);
            }
#pragma unroll
            for (int pf = 0; pf < 6; ++pf) {
                int col = pf * 16 + l15 + kw;   // padded col = out_col + kw
                int row = orow + kh;
                int S = (l4 ^ (col & 3) ^ ((col >> 2) & 3)) & 3;
                int slot = (row * 100 + col) * 4 + S;
                bf16x8 Bh = sX[0][slot];
                bf16x8 Bl = sX[1][slot];
#pragma unroll
                for (int q = 0; q < 2; ++q) {
                    acc[q][pf] = __builtin_amdgcn_mfma_f32_16x16x32_bf16(Ah[q], Bh, acc[q][pf], 0, 0, 0);
                    acc[q][pf] = __builtin_amdgcn_mfma_f32_16x16x32_bf16(Ah[q], Bl, acc[q][pf], 0, 0, 0);
                    acc[q][pf] = __builtin_amdgcn_mfma_f32_16x16x32_bf16(Al[q], Bh, acc[q][pf], 0, 0, 0);
                }
            }
        }
    }

    // ---- epilogue: D col = lane&15 (px), row = (lane>>4)*4 + reg (oc) ----
    const int orow_g = h0 + orow;
#pragma unroll
    for (int q = 0; q < 2; ++q) {
#pragma unroll
        for (int rg = 0; rg < 4; ++rg) {
            int oc = oh * 32 + q * 16 + l4 * 4 + rg;
            float bias = bk[b * 64 + oc];
            float* op = out + ((size_t)b * OB + oc) * HW + orow_g * 96;
#pragma unroll
            for (int pf = 0; pf < 6; ++pf) {
                int cc = pf * 16 + l15;
                float v = acc[q][pf][rg] + bias;
                if (FINAL) {
                    const float* xp = x + ((size_t)b * 64 + oc) * HW + orow_g * 96;
                    op[cc] = 0.2f * v + xp[cc];
                } else {
                    op[cc] = (v >= 0.f) ? v : 0.2f * v;
                }
            }
        }
    }
}

// ---------------------------------------------------------------------------
extern "C" void kernel_launch(void* const* d_in, const int* in_sizes, int n_in,
                              void* d_out, int out_size, void* d_ws, size_t ws_size,
                              hipStream_t stream) {
    const float* x = (const float*)d_in[0];
    float* out = (float*)d_out;

    // ws layout:
    float* F = (float*)d_ws;                               // [16][256][9216] x1..x4 (fp32)
    u16* PWH = (u16*)(F + (size_t)16 * 256 * HW);          // packed hi weights
    u16* PWL = PWH + (size_t)16 * 10 * 9 * 2048;           // packed lo weights
    float* pooled = (float*)(PWL + (size_t)16 * 10 * 9 * 2048);  // [16][320]
    float* attn = pooled + 16 * 320;                       // [16][8]
    float* bk = attn + 16 * 8;                             // [16][64]

    const int cins[5] = {64, 128, 192, 256, 320};
    dim3 cgrid(48, 16);

    for (int li = 0; li < 5; ++li) {
        const float* w   = (const float*)d_in[1 + li * 6 + 0];
        const float* bb  = (const float*)d_in[1 + li * 6 + 1];
        const float* aw1 = (const float*)d_in[1 + li * 6 + 2];
        const float* ab1 = (const float*)d_in[1 + li * 6 + 3];
        const float* aw2 = (const float*)d_in[1 + li * 6 + 4];
        const float* ab2 = (const float*)d_in[1 + li * 6 + 5];
        const int cin = cins[li];
        const int hid = cin / 4;
        const int nch = cin / 32;

        if (li == 0)
            pooled_kernel<<<dim3(16 * 64), 256, 0, stream>>>(x, 64, 0, pooled, 0);
        else
            pooled_kernel<<<dim3(16 * 64), 256, 0, stream>>>(F, 256, (li - 1) * 64, pooled, li * 64);

        attn_kernel<<<dim3(16), 128, 0, stream>>>(pooled, aw1, ab1, aw2, ab2, bb,
                                                  attn, bk, cin, hid);

        pack_weights<<<dim3(9 * nch), 256, 0, stream>>>(w, attn, PWH, PWL, cin);

        switch (li) {
            case 0: conv_mfma< 64, false><<<cgrid, 256, 0, stream>>>(x, F, PWH, PWL, bk, F + (size_t)0 * 64 * HW, 256); break;
            case 1: conv_mfma<128, false><<<cgrid, 256, 0, stream>>>(x, F, PWH, PWL, bk, F + (size_t)1 * 64 * HW, 256); break;
            case 2: conv_mfma<192, false><<<cgrid, 256, 0, stream>>>(x, F, PWH, PWL, bk, F + (size_t)2 * 64 * HW, 256); break;
            case 3: conv_mfma<256, false><<<cgrid, 256, 0, stream>>>(x, F, PWH, PWL, bk, F + (size_t)3 * 64 * HW, 256); break;
            case 4: conv_mfma<320, true ><<<cgrid, 256, 0, stream>>>(x, F, PWH, PWL, bk, out, 64); break;
        }
    }
}